// Round 1
// baseline (8561.716 us; speedup 1.0000x reference)
//
#include <hip/hip_runtime.h>

#define NTOK 8192
#define HID 2048
#define ITR 7168
#define NE 8
#define BK 64

typedef __attribute__((ext_vector_type(8))) short short8;
typedef __attribute__((ext_vector_type(8))) __bf16 bf16x8;
typedef __attribute__((ext_vector_type(4))) float f32x4;

__device__ __forceinline__ unsigned short f2bf(float f) {
  unsigned int u = __float_as_uint(f);
  u += 0x7FFFu + ((u >> 16) & 1u);   // round-to-nearest-even
  return (unsigned short)(u >> 16);
}

__device__ __forceinline__ f32x4 mfma_bf16(short8 a, short8 b, f32x4 c) {
  union U { short8 s; bf16x8 b; };
  U ua; ua.s = a;
  U ub; ub.s = b;
  return __builtin_amdgcn_mfma_f32_16x16x32_bf16(ua.b, ub.b, c, 0, 0, 0);
}

// ---------------- router: logits -> top2 -> pair lists ----------------
__global__ __launch_bounds__(256) void moe_router(
    const float* __restrict__ x, const float* __restrict__ gw,
    int* __restrict__ cnt, int* __restrict__ pair_token, float* __restrict__ pair_w) {
  int wave = threadIdx.x >> 6;
  int lane = threadIdx.x & 63;
  int t = blockIdx.x * 4 + wave;
  const float4* xr = reinterpret_cast<const float4*>(x + (size_t)t * HID);
  float acc[NE];
#pragma unroll
  for (int e = 0; e < NE; ++e) acc[e] = 0.f;
#pragma unroll
  for (int j = 0; j < 8; ++j) {
    int c = lane + 64 * j;                 // float4 chunk 0..511
    float4 xv = xr[c];
#pragma unroll
    for (int e = 0; e < NE; ++e) {
      float4 gv = reinterpret_cast<const float4*>(gw + (size_t)e * HID)[c];
      acc[e] += xv.x * gv.x + xv.y * gv.y + xv.z * gv.z + xv.w * gv.w;
    }
  }
#pragma unroll
  for (int e = 0; e < NE; ++e) {
    float s = acc[e];
#pragma unroll
    for (int m = 32; m > 0; m >>= 1) s += __shfl_xor(s, m);
    acc[e] = s;
  }
  if (lane == 0) {
    int e0 = 0; float l0 = acc[0];
#pragma unroll
    for (int e = 1; e < NE; ++e) if (acc[e] > l0) { l0 = acc[e]; e0 = e; }
    int e1 = -1; float l1 = -3.0e38f;
#pragma unroll
    for (int e = 0; e < NE; ++e) if (e != e0 && acc[e] > l1) { l1 = acc[e]; e1 = e; }
    float z = __expf(l1 - l0);             // <= 1
    float w0 = 1.f / (1.f + z);
    float w1 = z / (1.f + z);
    int p0 = atomicAdd(&cnt[e0], 1);
    pair_token[e0 * NTOK + p0] = t;
    pair_w[e0 * NTOK + p0] = w0;
    int p1 = atomicAdd(&cnt[e1], 1);
    pair_token[e1 * NTOK + p1] = t;
    pair_w[e1 * NTOK + p1] = w1;
  }
}

__global__ void moe_scan(const int* __restrict__ cnt, int* __restrict__ base) {
  if (threadIdx.x == 0) {
    int s = 0;
#pragma unroll
    for (int e = 0; e < NE; ++e) { base[e] = s; s += cnt[e]; }
  }
}

// ---------------- x -> bf16 ----------------
__global__ __launch_bounds__(256) void moe_cvt_x(const float* __restrict__ x,
                                                 unsigned short* __restrict__ xb) {
  size_t i = (size_t)blockIdx.x * 256 + threadIdx.x;   // 8 elems per thread
  const float4* p = reinterpret_cast<const float4*>(x) + i * 2;
  float4 a = p[0], b = p[1];
  union { unsigned short us[8]; short8 v; } u;
  u.us[0] = f2bf(a.x); u.us[1] = f2bf(a.y); u.us[2] = f2bf(a.z); u.us[3] = f2bf(a.w);
  u.us[4] = f2bf(b.x); u.us[5] = f2bf(b.y); u.us[6] = f2bf(b.z); u.us[7] = f2bf(b.w);
  reinterpret_cast<short8*>(xb)[i] = u.v;
}

// stage a [128][BK] bf16 tile from fp32 weights (row stride ldk), XOR-swizzled
__device__ __forceinline__ void stage_w_tile(const float* __restrict__ src, int ldk, int k0,
                                             unsigned short* __restrict__ dst, int tid) {
#pragma unroll
  for (int i = 0; i < 4; ++i) {
    int c = tid + 256 * i;         // 0..1023 chunks of 8 elems
    int row = c >> 3;
    int ch = c & 7;
    const float4* s = reinterpret_cast<const float4*>(src + (size_t)row * ldk + k0 + ch * 8);
    float4 f0 = s[0], f1 = s[1];
    union { unsigned short us[8]; short8 v; } u;
    u.us[0] = f2bf(f0.x); u.us[1] = f2bf(f0.y); u.us[2] = f2bf(f0.z); u.us[3] = f2bf(f0.w);
    u.us[4] = f2bf(f1.x); u.us[5] = f2bf(f1.y); u.us[6] = f2bf(f1.z); u.us[7] = f2bf(f1.w);
    *reinterpret_cast<short8*>(reinterpret_cast<char*>(dst) + row * (BK * 2) +
                               ((ch ^ (row & 7)) * 16)) = u.v;
  }
}

__device__ __forceinline__ short8 read_frag(const unsigned short* base, int row, int kelem) {
  return *reinterpret_cast<const short8*>(
      reinterpret_cast<const char*>(base) + ((row * (BK * 2) + kelem * 2) ^ ((row & 7) << 4)));
}

// ---------------- GEMM1: g = silu(x@w1^T) * (x@w3^T), gathered rows ----------------
__global__ __launch_bounds__(256, 2) void moe_gemm1(
    const unsigned short* __restrict__ xb, const float* __restrict__ w1,
    const float* __restrict__ w3, const int* __restrict__ cnt, const int* __restrict__ base,
    const int* __restrict__ pair_token, unsigned short* __restrict__ g) {
  int e = blockIdx.z;
  int n_e = cnt[e];
  int rowTile = blockIdx.x;                 // row fastest -> B-panel L2 reuse
  if (rowTile * 128 >= n_e) return;
  int colTile = blockIdx.y;

  __shared__ unsigned short lds[3 * 128 * BK];
  unsigned short* A = lds;
  unsigned short* B1 = lds + 128 * BK;
  unsigned short* B3 = lds + 2 * 128 * BK;

  int tid = threadIdx.x;
  int lane = tid & 63;
  int wv = tid >> 6;
  int wr = wv >> 1, wc = wv & 1;
  int lr = lane & 15;
  int lk = (lane >> 4) * 8;

  int slotP = e * NTOK + rowTile * 128;     // pair-array base
  int slotG = base[e] + rowTile * 128;      // compact g-row base
  const float* w1e = w1 + (size_t)e * ITR * HID + (size_t)colTile * 128 * HID;
  const float* w3e = w3 + (size_t)e * ITR * HID + (size_t)colTile * 128 * HID;

  f32x4 acc1[4][4], acc3[4][4];
#pragma unroll
  for (int m = 0; m < 4; ++m)
#pragma unroll
    for (int n = 0; n < 4; ++n) {
      acc1[m][n] = (f32x4){0.f, 0.f, 0.f, 0.f};
      acc3[m][n] = (f32x4){0.f, 0.f, 0.f, 0.f};
    }

  for (int k0 = 0; k0 < HID; k0 += BK) {
    __syncthreads();
    // stage A (gathered bf16 rows)
#pragma unroll
    for (int i = 0; i < 4; ++i) {
      int c = tid + 256 * i;
      int row = c >> 3, ch = c & 7;
      short8 v = {0, 0, 0, 0, 0, 0, 0, 0};
      if (rowTile * 128 + row < n_e) {
        int tok = pair_token[slotP + row];
        v = *reinterpret_cast<const short8*>(xb + (size_t)tok * HID + k0 + ch * 8);
      }
      *reinterpret_cast<short8*>(reinterpret_cast<char*>(A) + row * (BK * 2) +
                                 ((ch ^ (row & 7)) * 16)) = v;
    }
    stage_w_tile(w1e, HID, k0, B1, tid);
    stage_w_tile(w3e, HID, k0, B3, tid);
    __syncthreads();

#pragma unroll
    for (int kk = 0; kk < BK; kk += 32) {
      short8 av[4];
#pragma unroll
      for (int m = 0; m < 4; ++m) av[m] = read_frag(A, wr * 64 + m * 16 + lr, kk + lk);
#pragma unroll
      for (int n = 0; n < 4; ++n) {
        short8 b1v = read_frag(B1, wc * 64 + n * 16 + lr, kk + lk);
        short8 b3v = read_frag(B3, wc * 64 + n * 16 + lr, kk + lk);
#pragma unroll
        for (int m = 0; m < 4; ++m) {
          acc1[m][n] = mfma_bf16(av[m], b1v, acc1[m][n]);
          acc3[m][n] = mfma_bf16(av[m], b3v, acc3[m][n]);
        }
      }
    }
  }

#pragma unroll
  for (int m = 0; m < 4; ++m) {
    int rbase = wr * 64 + m * 16 + ((lane >> 4) << 2);
#pragma unroll
    for (int r = 0; r < 4; ++r) {
      int rt = rbase + r;
      if (rowTile * 128 + rt < n_e) {
        unsigned short* grow = g + (size_t)(slotG + rt) * ITR + colTile * 128 + wc * 64;
#pragma unroll
        for (int n = 0; n < 4; ++n) {
          float h1 = acc1[m][n][r], h3 = acc3[m][n][r];
          float sl = h1 / (1.f + __expf(-h1));
          grow[n * 16 + lr] = f2bf(sl * h3);
        }
      }
    }
  }
}

// ---------------- GEMM2: out += w * (g @ w2^T), scatter ----------------
__global__ __launch_bounds__(256, 2) void moe_gemm2(
    const unsigned short* __restrict__ g, const float* __restrict__ w2,
    const int* __restrict__ cnt, const int* __restrict__ base,
    const int* __restrict__ pair_token, const float* __restrict__ pair_w,
    float* __restrict__ out) {
  int e = blockIdx.z;
  int n_e = cnt[e];
  int rowTile = blockIdx.x;
  if (rowTile * 128 >= n_e) return;
  int colTile = blockIdx.y;                 // 0..15

  __shared__ unsigned short lds[2 * 128 * BK];
  unsigned short* A = lds;
  unsigned short* B = lds + 128 * BK;

  int tid = threadIdx.x;
  int lane = tid & 63;
  int wv = tid >> 6;
  int wr = wv >> 1, wc = wv & 1;
  int lr = lane & 15;
  int lk = (lane >> 4) * 8;

  int slotP = e * NTOK + rowTile * 128;
  int slotG = base[e] + rowTile * 128;
  const float* w2e = w2 + (size_t)e * HID * ITR + (size_t)colTile * 128 * ITR;

  f32x4 acc[4][4];
#pragma unroll
  for (int m = 0; m < 4; ++m)
#pragma unroll
    for (int n = 0; n < 4; ++n) acc[m][n] = (f32x4){0.f, 0.f, 0.f, 0.f};

  for (int k0 = 0; k0 < ITR; k0 += BK) {
    __syncthreads();
#pragma unroll
    for (int i = 0; i < 4; ++i) {
      int c = tid + 256 * i;
      int row = c >> 3, ch = c & 7;
      short8 v = {0, 0, 0, 0, 0, 0, 0, 0};
      if (rowTile * 128 + row < n_e)
        v = *reinterpret_cast<const short8*>(g + (size_t)(slotG + row) * ITR + k0 + ch * 8);
      *reinterpret_cast<short8*>(reinterpret_cast<char*>(A) + row * (BK * 2) +
                                 ((ch ^ (row & 7)) * 16)) = v;
    }
    stage_w_tile(w2e, ITR, k0, B, tid);
    __syncthreads();

#pragma unroll
    for (int kk = 0; kk < BK; kk += 32) {
      short8 av[4];
#pragma unroll
      for (int m = 0; m < 4; ++m) av[m] = read_frag(A, wr * 64 + m * 16 + lr, kk + lk);
#pragma unroll
      for (int n = 0; n < 4; ++n) {
        short8 bv = read_frag(B, wc * 64 + n * 16 + lr, kk + lk);
#pragma unroll
        for (int m = 0; m < 4; ++m) acc[m][n] = mfma_bf16(av[m], bv, acc[m][n]);
      }
    }
  }

#pragma unroll
  for (int m = 0; m < 4; ++m) {
    int rbase = wr * 64 + m * 16 + ((lane >> 4) << 2);
#pragma unroll
    for (int r = 0; r < 4; ++r) {
      int rt = rbase + r;
      if (rowTile * 128 + rt < n_e) {
        int slot = slotP + rt;
        int tok = pair_token[slot];
        float wgt = pair_w[slot];
        float* orow = out + (size_t)tok * HID + colTile * 128 + wc * 64;
#pragma unroll
        for (int n = 0; n < 4; ++n) atomicAdd(&orow[n * 16 + lr], wgt * acc[m][n][r]);
      }
    }
  }
}

extern "C" void kernel_launch(void* const* d_in, const int* in_sizes, int n_in,
                              void* d_out, int out_size, void* d_ws, size_t ws_size,
                              hipStream_t stream) {
  const float* x = (const float*)d_in[0];
  const float* gate_w = (const float*)d_in[1];
  const float* w1 = (const float*)d_in[2];
  const float* w3 = (const float*)d_in[3];
  const float* w2 = (const float*)d_in[4];
  float* out = (float*)d_out;

  char* ws = (char*)d_ws;
  const size_t G_BYTES = (size_t)2 * NTOK * 2 * ITR;          // 16384 x 7168 bf16 = 235 MB
  const size_t XB_BYTES = (size_t)NTOK * HID * 2;             // 33.5 MB
  unsigned short* g = (unsigned short*)ws;
  unsigned short* xb = (unsigned short*)(ws + G_BYTES);
  int* pair_token = (int*)(ws + G_BYTES + XB_BYTES);
  float* pair_w = (float*)(ws + G_BYTES + XB_BYTES + (size_t)NE * NTOK * 4);
  int* cnt = (int*)(ws + G_BYTES + XB_BYTES + (size_t)2 * NE * NTOK * 4);
  int* base = cnt + NE;

  hipMemsetAsync(cnt, 0, 2 * NE * sizeof(int), stream);
  hipMemsetAsync(d_out, 0, (size_t)NTOK * HID * sizeof(float), stream);

  moe_router<<<NTOK / 4, 256, 0, stream>>>(x, gate_w, cnt, pair_token, pair_w);
  moe_scan<<<1, 64, 0, stream>>>(cnt, base);
  moe_cvt_x<<<(NTOK * HID) / (256 * 8), 256, 0, stream>>>(x, xb);
  moe_gemm1<<<dim3(NTOK / 128, ITR / 128, NE), 256, 0, stream>>>(xb, w1, w3, cnt, base,
                                                                 pair_token, g);
  moe_gemm2<<<dim3(NTOK / 128, HID / 128, NE), 256, 0, stream>>>(g, w2, cnt, base, pair_token,
                                                                 pair_w, out);
}

// Round 2
// 4147.217 us; speedup vs baseline: 2.0644x; 2.0644x over previous
//
#include <hip/hip_runtime.h>

#define NTOK 8192
#define HID 2048
#define ITR 7168
#define NE 8
#define BK 64
#define TILE (128 * BK)   // elems per 128xBK bf16 tile (16 KB)

typedef __attribute__((ext_vector_type(8))) short short8;
typedef __attribute__((ext_vector_type(8))) __bf16 bf16x8;
typedef __attribute__((ext_vector_type(4))) float f32x4;

__device__ __forceinline__ unsigned short f2bf(float f) {
  unsigned int u = __float_as_uint(f);
  u += 0x7FFFu + ((u >> 16) & 1u);   // round-to-nearest-even
  return (unsigned short)(u >> 16);
}

__device__ __forceinline__ f32x4 mfma_bf16(short8 a, short8 b, f32x4 c) {
  union U { short8 s; bf16x8 b; };
  U ua; ua.s = a;
  U ub; ub.s = b;
  return __builtin_amdgcn_mfma_f32_16x16x32_bf16(ua.b, ub.b, c, 0, 0, 0);
}

typedef __attribute__((address_space(1))) const unsigned int g_u32;
typedef __attribute__((address_space(3))) unsigned int l_u32;

// async global->LDS, 16B per lane; dst is wave-uniform base, src is per-lane
__device__ __forceinline__ void gload16(const unsigned short* src, unsigned short* dst) {
  __builtin_amdgcn_global_load_lds((g_u32*)src, (l_u32*)dst, 16, 0, 0);
}

// swizzled read: frag of 8 bf16 at (row, kelem) from a [128][BK] tile
__device__ __forceinline__ short8 read_frag(const unsigned short* base, int row, int kelem) {
  return *reinterpret_cast<const short8*>(
      reinterpret_cast<const char*>(base) + ((row * (BK * 2) + kelem * 2) ^ ((row & 7) << 4)));
}

// ---------------- router: logits -> top2 -> pair lists ----------------
__global__ __launch_bounds__(256) void moe_router(
    const float* __restrict__ x, const float* __restrict__ gw,
    int* __restrict__ cnt, int* __restrict__ pair_token, float* __restrict__ pair_w) {
  int wave = threadIdx.x >> 6;
  int lane = threadIdx.x & 63;
  int t = blockIdx.x * 4 + wave;
  const float4* xr = reinterpret_cast<const float4*>(x + (size_t)t * HID);
  float acc[NE];
#pragma unroll
  for (int e = 0; e < NE; ++e) acc[e] = 0.f;
#pragma unroll
  for (int j = 0; j < 8; ++j) {
    int c = lane + 64 * j;
    float4 xv = xr[c];
#pragma unroll
    for (int e = 0; e < NE; ++e) {
      float4 gv = reinterpret_cast<const float4*>(gw + (size_t)e * HID)[c];
      acc[e] += xv.x * gv.x + xv.y * gv.y + xv.z * gv.z + xv.w * gv.w;
    }
  }
#pragma unroll
  for (int e = 0; e < NE; ++e) {
    float s = acc[e];
#pragma unroll
    for (int m = 32; m > 0; m >>= 1) s += __shfl_xor(s, m);
    acc[e] = s;
  }
  if (lane == 0) {
    int e0 = 0; float l0 = acc[0];
#pragma unroll
    for (int e = 1; e < NE; ++e) if (acc[e] > l0) { l0 = acc[e]; e0 = e; }
    int e1 = -1; float l1 = -3.0e38f;
#pragma unroll
    for (int e = 0; e < NE; ++e) if (e != e0 && acc[e] > l1) { l1 = acc[e]; e1 = e; }
    float z = __expf(l1 - l0);
    float w0 = 1.f / (1.f + z);
    float w1 = z / (1.f + z);
    int p0 = atomicAdd(&cnt[e0], 1);
    pair_token[e0 * NTOK + p0] = t;
    pair_w[e0 * NTOK + p0] = w0;
    int p1 = atomicAdd(&cnt[e1], 1);
    pair_token[e1 * NTOK + p1] = t;
    pair_w[e1 * NTOK + p1] = w1;
  }
}

__global__ void moe_scan(const int* __restrict__ cnt, int* __restrict__ base) {
  if (threadIdx.x == 0) {
    int s = 0;
#pragma unroll
    for (int e = 0; e < NE; ++e) { base[e] = s; s += cnt[e]; }
  }
}

// ---------------- fp32 -> bf16 bulk convert (8 elems/thread, exact grids) ----------------
__global__ __launch_bounds__(256) void moe_cvt(const float* __restrict__ src,
                                               unsigned short* __restrict__ dst) {
  size_t i = (size_t)blockIdx.x * 256 + threadIdx.x;
  const float4* p = reinterpret_cast<const float4*>(src) + i * 2;
  float4 a = p[0], b = p[1];
  union { unsigned short us[8]; short8 v; } u;
  u.us[0] = f2bf(a.x); u.us[1] = f2bf(a.y); u.us[2] = f2bf(a.z); u.us[3] = f2bf(a.w);
  u.us[4] = f2bf(b.x); u.us[5] = f2bf(b.y); u.us[6] = f2bf(b.z); u.us[7] = f2bf(b.w);
  reinterpret_cast<short8*>(dst)[i] = u.v;
}

// ================= PATH A: bf16 weights + global_load_lds + 2-phase dbuf =================

// GEMM1: g = silu(x@w1^T) * (x@w3^T)
__global__ __launch_bounds__(256) void moe_gemm1_a(
    const unsigned short* __restrict__ xb, const unsigned short* __restrict__ w1b,
    const unsigned short* __restrict__ w3b, const int* __restrict__ cnt,
    const int* __restrict__ base, const int* __restrict__ pair_token,
    unsigned short* __restrict__ g) {
  int e = blockIdx.z;
  int n_e = cnt[e];
  int rowTile = blockIdx.x;
  if (rowTile * 128 >= n_e) return;
  int colTile = blockIdx.y;

  __shared__ unsigned short lds[2 * 3 * TILE];   // 96 KB: dbuf x {A,B1,B3}

  int tid = threadIdx.x;
  int lane = tid & 63;
  int wv = tid >> 6;
  int wr = wv >> 1, wc = wv & 1;
  int lr = lane & 15;
  int lk = (lane >> 4) * 8;
  int lrow8 = lane >> 3, lch = lane & 7;

  int slotP = e * NTOK + rowTile * 128;
  int slotG = base[e] + rowTile * 128;
  const unsigned short* w1e = w1b + (size_t)e * ITR * HID + (size_t)colTile * 128 * HID;
  const unsigned short* w3e = w3b + (size_t)e * ITR * HID + (size_t)colTile * 128 * HID;

  // per-lane pre-swizzled source pointers (4 gload16 instrs per tile per wave)
  const unsigned short* asrc[4];
  const unsigned short* b1src[4];
  const unsigned short* b3src[4];
#pragma unroll
  for (int i = 0; i < 4; ++i) {
    int row = wv * 32 + i * 8 + lrow8;           // row within 128-tile
    int chs = ((lch ^ (row & 7)) * 8);           // swizzled chunk offset (elems)
    int tok = pair_token[slotP + ((rowTile * 128 + row < n_e) ? row : 0)];
    asrc[i] = xb + (size_t)tok * HID + chs;
    b1src[i] = w1e + (size_t)row * HID + chs;
    b3src[i] = w3e + (size_t)row * HID + chs;
  }

  f32x4 acc1[4][4], acc3[4][4];
#pragma unroll
  for (int m = 0; m < 4; ++m)
#pragma unroll
    for (int n = 0; n < 4; ++n) {
      acc1[m][n] = (f32x4){0.f, 0.f, 0.f, 0.f};
      acc3[m][n] = (f32x4){0.f, 0.f, 0.f, 0.f};
    }

#define STAGE1(buf, k0)                                                          \
  do {                                                                           \
    unsigned short* Lb = lds + (buf) * 3 * TILE + (wv * 32) * BK;                \
    _Pragma("unroll") for (int i = 0; i < 4; ++i) {                              \
      gload16(asrc[i] + (k0), Lb + i * 8 * BK);                                  \
      gload16(b1src[i] + (k0), Lb + TILE + i * 8 * BK);                          \
      gload16(b3src[i] + (k0), Lb + 2 * TILE + i * 8 * BK);                      \
    }                                                                            \
  } while (0)

  const int nt = HID / BK;   // 32
  int cur = 0;
  STAGE1(0, 0);
  __syncthreads();           // vmcnt(0) drain + barrier: buf0 ready

  for (int t = 0; t < nt; ++t) {
    if (t + 1 < nt) STAGE1(cur ^ 1, (t + 1) * BK);
    const unsigned short* A = lds + cur * 3 * TILE;
    const unsigned short* B1 = A + TILE;
    const unsigned short* B3 = A + 2 * TILE;
#pragma unroll
    for (int kk = 0; kk < BK; kk += 32) {
      short8 av[4];
#pragma unroll
      for (int m = 0; m < 4; ++m) av[m] = read_frag(A, wr * 64 + m * 16 + lr, kk + lk);
#pragma unroll
      for (int n = 0; n < 4; ++n) {
        short8 b1v = read_frag(B1, wc * 64 + n * 16 + lr, kk + lk);
        short8 b3v = read_frag(B3, wc * 64 + n * 16 + lr, kk + lk);
#pragma unroll
        for (int m = 0; m < 4; ++m) {
          acc1[m][n] = mfma_bf16(av[m], b1v, acc1[m][n]);
          acc3[m][n] = mfma_bf16(av[m], b3v, acc3[m][n]);
        }
      }
    }
    __syncthreads();         // drains vmcnt (next buf loaded) + barrier
    cur ^= 1;
  }
#undef STAGE1

#pragma unroll
  for (int m = 0; m < 4; ++m) {
    int rbase = wr * 64 + m * 16 + ((lane >> 4) << 2);
#pragma unroll
    for (int r = 0; r < 4; ++r) {
      int rt = rbase + r;
      if (rowTile * 128 + rt < n_e) {
        unsigned short* grow = g + (size_t)(slotG + rt) * ITR + colTile * 128 + wc * 64;
#pragma unroll
        for (int n = 0; n < 4; ++n) {
          float h1 = acc1[m][n][r], h3 = acc3[m][n][r];
          float sl = h1 / (1.f + __expf(-h1));
          grow[n * 16 + lr] = f2bf(sl * h3);
        }
      }
    }
  }
}

// GEMM2: out += w * (g @ w2^T)
__global__ __launch_bounds__(256) void moe_gemm2_a(
    const unsigned short* __restrict__ g, const unsigned short* __restrict__ w2b,
    const int* __restrict__ cnt, const int* __restrict__ base,
    const int* __restrict__ pair_token, const float* __restrict__ pair_w,
    float* __restrict__ out) {
  int e = blockIdx.z;
  int n_e = cnt[e];
  int rowTile = blockIdx.x;
  if (rowTile * 128 >= n_e) return;
  int colTile = blockIdx.y;

  __shared__ unsigned short lds[2 * 2 * TILE];   // 64 KB: dbuf x {A,B}

  int tid = threadIdx.x;
  int lane = tid & 63;
  int wv = tid >> 6;
  int wr = wv >> 1, wc = wv & 1;
  int lr = lane & 15;
  int lk = (lane >> 4) * 8;
  int lrow8 = lane >> 3, lch = lane & 7;

  int slotP = e * NTOK + rowTile * 128;
  int slotG = base[e] + rowTile * 128;
  const unsigned short* w2e = w2b + (size_t)e * HID * ITR + (size_t)colTile * 128 * ITR;

  const unsigned short* asrc[4];
  const unsigned short* bsrc[4];
#pragma unroll
  for (int i = 0; i < 4; ++i) {
    int row = wv * 32 + i * 8 + lrow8;
    int chs = ((lch ^ (row & 7)) * 8);
    int rclamp = (rowTile * 128 + row < n_e) ? row : 0;
    asrc[i] = g + (size_t)(slotG + rclamp) * ITR + chs;   // g rows are compact -> dense
    bsrc[i] = w2e + (size_t)row * ITR + chs;
  }

  f32x4 acc[4][4];
#pragma unroll
  for (int m = 0; m < 4; ++m)
#pragma unroll
    for (int n = 0; n < 4; ++n) acc[m][n] = (f32x4){0.f, 0.f, 0.f, 0.f};

#define STAGE2(buf, k0)                                                          \
  do {                                                                           \
    unsigned short* Lb = lds + (buf) * 2 * TILE + (wv * 32) * BK;                \
    _Pragma("unroll") for (int i = 0; i < 4; ++i) {                              \
      gload16(asrc[i] + (k0), Lb + i * 8 * BK);                                  \
      gload16(bsrc[i] + (k0), Lb + TILE + i * 8 * BK);                           \
    }                                                                            \
  } while (0)

  const int nt = ITR / BK;   // 112
  int cur = 0;
  STAGE2(0, 0);
  __syncthreads();

  for (int t = 0; t < nt; ++t) {
    if (t + 1 < nt) STAGE2(cur ^ 1, (t + 1) * BK);
    const unsigned short* A = lds + cur * 2 * TILE;
    const unsigned short* B = A + TILE;
#pragma unroll
    for (int kk = 0; kk < BK; kk += 32) {
      short8 av[4];
#pragma unroll
      for (int m = 0; m < 4; ++m) av[m] = read_frag(A, wr * 64 + m * 16 + lr, kk + lk);
#pragma unroll
      for (int n = 0; n < 4; ++n) {
        short8 bv = read_frag(B, wc * 64 + n * 16 + lr, kk + lk);
#pragma unroll
        for (int m = 0; m < 4; ++m) acc[m][n] = mfma_bf16(av[m], bv, acc[m][n]);
      }
    }
    __syncthreads();
    cur ^= 1;
  }
#undef STAGE2

#pragma unroll
  for (int m = 0; m < 4; ++m) {
    int rbase = wr * 64 + m * 16 + ((lane >> 4) << 2);
#pragma unroll
    for (int r = 0; r < 4; ++r) {
      int rt = rbase + r;
      if (rowTile * 128 + rt < n_e) {
        int slot = slotP + rt;
        int tok = pair_token[slot];
        float wgt = pair_w[slot];
        float* orow = out + (size_t)tok * HID + colTile * 128 + wc * 64;
#pragma unroll
        for (int n = 0; n < 4; ++n) atomicAdd(&orow[n * 16 + lr], wgt * acc[m][n][r]);
      }
    }
  }
}

// ================= PATH B (fallback, round-1 kernels): fp32 weights =================

__device__ __forceinline__ void stage_w_tile(const float* __restrict__ src, int ldk, int k0,
                                             unsigned short* __restrict__ dst, int tid) {
#pragma unroll
  for (int i = 0; i < 4; ++i) {
    int c = tid + 256 * i;
    int row = c >> 3;
    int ch = c & 7;
    const float4* s = reinterpret_cast<const float4*>(src + (size_t)row * ldk + k0 + ch * 8);
    float4 f0 = s[0], f1 = s[1];
    union { unsigned short us[8]; short8 v; } u;
    u.us[0] = f2bf(f0.x); u.us[1] = f2bf(f0.y); u.us[2] = f2bf(f0.z); u.us[3] = f2bf(f0.w);
    u.us[4] = f2bf(f1.x); u.us[5] = f2bf(f1.y); u.us[6] = f2bf(f1.z); u.us[7] = f2bf(f1.w);
    *reinterpret_cast<short8*>(reinterpret_cast<char*>(dst) + row * (BK * 2) +
                               ((ch ^ (row & 7)) * 16)) = u.v;
  }
}

__global__ __launch_bounds__(256, 2) void moe_gemm1(
    const unsigned short* __restrict__ xb, const float* __restrict__ w1,
    const float* __restrict__ w3, const int* __restrict__ cnt, const int* __restrict__ base,
    const int* __restrict__ pair_token, unsigned short* __restrict__ g) {
  int e = blockIdx.z;
  int n_e = cnt[e];
  int rowTile = blockIdx.x;
  if (rowTile * 128 >= n_e) return;
  int colTile = blockIdx.y;

  __shared__ unsigned short lds[3 * TILE];
  unsigned short* A = lds;
  unsigned short* B1 = lds + TILE;
  unsigned short* B3 = lds + 2 * TILE;

  int tid = threadIdx.x;
  int lane = tid & 63;
  int wv = tid >> 6;
  int wr = wv >> 1, wc = wv & 1;
  int lr = lane & 15;
  int lk = (lane >> 4) * 8;

  int slotP = e * NTOK + rowTile * 128;
  int slotG = base[e] + rowTile * 128;
  const float* w1e = w1 + (size_t)e * ITR * HID + (size_t)colTile * 128 * HID;
  const float* w3e = w3 + (size_t)e * ITR * HID + (size_t)colTile * 128 * HID;

  f32x4 acc1[4][4], acc3[4][4];
#pragma unroll
  for (int m = 0; m < 4; ++m)
#pragma unroll
    for (int n = 0; n < 4; ++n) {
      acc1[m][n] = (f32x4){0.f, 0.f, 0.f, 0.f};
      acc3[m][n] = (f32x4){0.f, 0.f, 0.f, 0.f};
    }

  for (int k0 = 0; k0 < HID; k0 += BK) {
    __syncthreads();
#pragma unroll
    for (int i = 0; i < 4; ++i) {
      int c = tid + 256 * i;
      int row = c >> 3, ch = c & 7;
      short8 v = {0, 0, 0, 0, 0, 0, 0, 0};
      if (rowTile * 128 + row < n_e) {
        int tok = pair_token[slotP + row];
        v = *reinterpret_cast<const short8*>(xb + (size_t)tok * HID + k0 + ch * 8);
      }
      *reinterpret_cast<short8*>(reinterpret_cast<char*>(A) + row * (BK * 2) +
                                 ((ch ^ (row & 7)) * 16)) = v;
    }
    stage_w_tile(w1e, HID, k0, B1, tid);
    stage_w_tile(w3e, HID, k0, B3, tid);
    __syncthreads();

#pragma unroll
    for (int kk = 0; kk < BK; kk += 32) {
      short8 av[4];
#pragma unroll
      for (int m = 0; m < 4; ++m) av[m] = read_frag(A, wr * 64 + m * 16 + lr, kk + lk);
#pragma unroll
      for (int n = 0; n < 4; ++n) {
        short8 b1v = read_frag(B1, wc * 64 + n * 16 + lr, kk + lk);
        short8 b3v = read_frag(B3, wc * 64 + n * 16 + lr, kk + lk);
#pragma unroll
        for (int m = 0; m < 4; ++m) {
          acc1[m][n] = mfma_bf16(av[m], b1v, acc1[m][n]);
          acc3[m][n] = mfma_bf16(av[m], b3v, acc3[m][n]);
        }
      }
    }
  }

#pragma unroll
  for (int m = 0; m < 4; ++m) {
    int rbase = wr * 64 + m * 16 + ((lane >> 4) << 2);
#pragma unroll
    for (int r = 0; r < 4; ++r) {
      int rt = rbase + r;
      if (rowTile * 128 + rt < n_e) {
        unsigned short* grow = g + (size_t)(slotG + rt) * ITR + colTile * 128 + wc * 64;
#pragma unroll
        for (int n = 0; n < 4; ++n) {
          float h1 = acc1[m][n][r], h3 = acc3[m][n][r];
          float sl = h1 / (1.f + __expf(-h1));
          grow[n * 16 + lr] = f2bf(sl * h3);
        }
      }
    }
  }
}

__global__ __launch_bounds__(256, 2) void moe_gemm2(
    const unsigned short* __restrict__ g, const float* __restrict__ w2,
    const int* __restrict__ cnt, const int* __restrict__ base,
    const int* __restrict__ pair_token, const float* __restrict__ pair_w,
    float* __restrict__ out) {
  int e = blockIdx.z;
  int n_e = cnt[e];
  int rowTile = blockIdx.x;
  if (rowTile * 128 >= n_e) return;
  int colTile = blockIdx.y;

  __shared__ unsigned short lds[2 * TILE];
  unsigned short* A = lds;
  unsigned short* B = lds + TILE;

  int tid = threadIdx.x;
  int lane = tid & 63;
  int wv = tid >> 6;
  int wr = wv >> 1, wc = wv & 1;
  int lr = lane & 15;
  int lk = (lane >> 4) * 8;

  int slotP = e * NTOK + rowTile * 128;
  int slotG = base[e] + rowTile * 128;
  const float* w2e = w2 + (size_t)e * HID * ITR + (size_t)colTile * 128 * ITR;

  f32x4 acc[4][4];
#pragma unroll
  for (int m = 0; m < 4; ++m)
#pragma unroll
    for (int n = 0; n < 4; ++n) acc[m][n] = (f32x4){0.f, 0.f, 0.f, 0.f};

  for (int k0 = 0; k0 < ITR; k0 += BK) {
    __syncthreads();
#pragma unroll
    for (int i = 0; i < 4; ++i) {
      int c = tid + 256 * i;
      int row = c >> 3, ch = c & 7;
      short8 v = {0, 0, 0, 0, 0, 0, 0, 0};
      if (rowTile * 128 + row < n_e)
        v = *reinterpret_cast<const short8*>(g + (size_t)(slotG + row) * ITR + k0 + ch * 8);
      *reinterpret_cast<short8*>(reinterpret_cast<char*>(A) + row * (BK * 2) +
                                 ((ch ^ (row & 7)) * 16)) = v;
    }
    stage_w_tile(w2e, ITR, k0, B, tid);
    __syncthreads();

#pragma unroll
    for (int kk = 0; kk < BK; kk += 32) {
      short8 av[4];
#pragma unroll
      for (int m = 0; m < 4; ++m) av[m] = read_frag(A, wr * 64 + m * 16 + lr, kk + lk);
#pragma unroll
      for (int n = 0; n < 4; ++n) {
        short8 bv = read_frag(B, wc * 64 + n * 16 + lr, kk + lk);
#pragma unroll
        for (int m = 0; m < 4; ++m) acc[m][n] = mfma_bf16(av[m], bv, acc[m][n]);
      }
    }
  }

#pragma unroll
  for (int m = 0; m < 4; ++m) {
    int rbase = wr * 64 + m * 16 + ((lane >> 4) << 2);
#pragma unroll
    for (int r = 0; r < 4; ++r) {
      int rt = rbase + r;
      if (rowTile * 128 + rt < n_e) {
        int slot = slotP + rt;
        int tok = pair_token[slot];
        float wgt = pair_w[slot];
        float* orow = out + (size_t)tok * HID + colTile * 128 + wc * 64;
#pragma unroll
        for (int n = 0; n < 4; ++n) atomicAdd(&orow[n * 16 + lr], wgt * acc[m][n][r]);
      }
    }
  }
}

// ================= launch =================

extern "C" void kernel_launch(void* const* d_in, const int* in_sizes, int n_in,
                              void* d_out, int out_size, void* d_ws, size_t ws_size,
                              hipStream_t stream) {
  const float* x = (const float*)d_in[0];
  const float* gate_w = (const float*)d_in[1];
  const float* w1 = (const float*)d_in[2];
  const float* w3 = (const float*)d_in[3];
  const float* w2 = (const float*)d_in[4];
  float* out = (float*)d_out;

  char* ws = (char*)d_ws;
  const size_t WEL = (size_t)NE * ITR * HID;                 // elems per weight tensor
  const size_t G_BYTES = (size_t)NTOK * 2 * ITR * 2;         // 16384 x 7168 bf16
  const size_t XB_BYTES = (size_t)NTOK * HID * 2;
  const size_t PAIR_BYTES = (size_t)NE * NTOK * 4;
  const size_t WB_BYTES = WEL * 2;                           // one bf16 weight tensor

  unsigned short* g = (unsigned short*)ws;
  unsigned short* xb = (unsigned short*)(ws + G_BYTES);
  int* pair_token = (int*)(ws + G_BYTES + XB_BYTES);
  float* pair_w = (float*)(ws + G_BYTES + XB_BYTES + PAIR_BYTES);
  int* cnt = (int*)(ws + G_BYTES + XB_BYTES + 2 * PAIR_BYTES);
  int* base = cnt + NE;
  char* wbase = ws + G_BYTES + XB_BYTES + 2 * PAIR_BYTES + 256;
  unsigned short* w1b = (unsigned short*)wbase;
  unsigned short* w3b = (unsigned short*)(wbase + WB_BYTES);
  unsigned short* w2b = (unsigned short*)(wbase + 2 * WB_BYTES);

  const size_t NEED_A = G_BYTES + XB_BYTES + 2 * PAIR_BYTES + 256 + 3 * WB_BYTES;

  hipMemsetAsync(cnt, 0, 2 * NE * sizeof(int), stream);
  hipMemsetAsync(d_out, 0, (size_t)NTOK * HID * sizeof(float), stream);

  moe_router<<<NTOK / 4, 256, 0, stream>>>(x, gate_w, cnt, pair_token, pair_w);
  moe_scan<<<1, 64, 0, stream>>>(cnt, base);
  moe_cvt<<<(NTOK * HID) / 2048, 256, 0, stream>>>(x, xb);

  if (ws_size >= NEED_A) {
    const int WGRID = (int)(WEL / 2048);                     // 57344
    moe_cvt<<<WGRID, 256, 0, stream>>>(w1, w1b);
    moe_cvt<<<WGRID, 256, 0, stream>>>(w3, w3b);
    moe_cvt<<<WGRID, 256, 0, stream>>>(w2, w2b);
    moe_gemm1_a<<<dim3(NTOK / 128, ITR / 128, NE), 256, 0, stream>>>(
        xb, w1b, w3b, cnt, base, pair_token, g);
    moe_gemm2_a<<<dim3(NTOK / 128, HID / 128, NE), 256, 0, stream>>>(
        g, w2b, cnt, base, pair_token, pair_w, out);
  } else {
    moe_gemm1<<<dim3(NTOK / 128, ITR / 128, NE), 256, 0, stream>>>(xb, w1, w3, cnt, base,
                                                                   pair_token, g);
    moe_gemm2<<<dim3(NTOK / 128, HID / 128, NE), 256, 0, stream>>>(g, w2, cnt, base,
                                                                   pair_token, pair_w, out);
  }
}